// Round 6
// baseline (656.647 us; speedup 1.0000x reference)
//
#include <hip/hip_runtime.h>
#include <math.h>

#define N_TOK 32768
#define K_CODES 4096
#define DIM 512
#define COMMIT 0.25f
#define NCAND 8
#define NSPLIT 4
#define SPLIT_CODES 1024
#define PANELS 4            // 256-code panels per split
#define BIAS 0.125f

typedef short s16x8 __attribute__((ext_vector_type(8)));
typedef float f32x16 __attribute__((ext_vector_type(16)));
typedef unsigned int uint32;
typedef unsigned long long u64;
typedef unsigned short u16;

__device__ __forceinline__ u16 f2bf(float f) {
    uint32 b = __float_as_uint(f);
    return (u16)((b + 0x7FFFu + ((b >> 16) & 1u)) >> 16);
}

__device__ __forceinline__ void ins3(uint32 key, uint32& a, uint32& b, uint32& c) {
    if (key < c) {
        if (key < a)      { c = b; b = a; a = key; }
        else if (key < b) { c = b; b = key; }
        else              { c = key; }
    }
}

// ---------------------------------------------------------------------------
// Fused: numpy-exact fp32 row sum-of-squares (R3-verified pairwise structure)
// + fp32->bf16 (RNE) bulk convert in one pass over the input.
// ---------------------------------------------------------------------------
__global__ __launch_bounds__(256) void fuse_prep_kernel(const float* __restrict__ a,
                                                        float* __restrict__ osq,
                                                        u16* __restrict__ obf,
                                                        int nrows, int n4) {
    #pragma clang fp contract(off)
    // phase A: numpy pairwise rowsq (exact structure from R3 — do not touch)
    {
        const int gw   = (blockIdx.x * 256 + threadIdx.x) >> 6;
        const int lane = threadIdx.x & 63;
        const int row  = gw * 8 + (lane >> 3);
        const int j    = lane & 7;
        if (row < nrows) {
            const float* p = a + (size_t)row * DIM;
            float blk[4];
            #pragma unroll
            for (int b = 0; b < 4; ++b) {
                const float* q = p + b * 128;
                float v = q[j];
                float r = v * v;
                for (int i = 8; i < 128; i += 8) { float u = q[i + j]; r += u * u; }
                float s1 = r  + __shfl_xor(r, 1);
                float s2 = s1 + __shfl_xor(s1, 2);
                float s3 = s2 + __shfl_xor(s2, 4);
                blk[b] = s3;
            }
            float res = (blk[0] + blk[1]) + (blk[2] + blk[3]);
            if (j == 0) osq[row] = res;
        }
    }
    // phase B: bf16 convert, grid-stride
    int i = blockIdx.x * 256 + threadIdx.x;
    int stride = gridDim.x * 256;
    for (; i < n4; i += stride) {
        float4 v = ((const float4*)a)[i];
        ushort4 o;
        o.x = f2bf(v.x); o.y = f2bf(v.y); o.z = f2bf(v.z); o.w = f2bf(v.w);
        ((ushort4*)obf)[i] = o;
    }
}

// ---------------------------------------------------------------------------
// MFMA bf16 screen, 32x32x16 shape. Grid: (token-panels=256, splits=4).
// Block 256 thr = 4 waves (2 code-halves x 2 token-cols); block tile per
// panel-iter = 256 codes x 128 tokens; wave tile 128 codes x 64 tokens
// (4x2 grid of 32x32x16 -> 6 ds_read_b128 per 8 MFMAs). BK=64 single-buffer
// LDS 48KB, 16B-quantum XOR swizzle. A=codes so C/D col(lane&31)=token.
// Per-lane top-3 keys per token-col: key = bits(score+BIAS)&~0xFFF | code.
// ---------------------------------------------------------------------------
__global__ __launch_bounds__(256, 2) void screen_kernel(const u16* __restrict__ xb,
                                                        const u16* __restrict__ wb,
                                                        const float* __restrict__ w2f,
                                                        uint32* __restrict__ candPart) {
    __shared__ __attribute__((aligned(16))) u16 POOL[24576];  // A:0..16383, B:16384..24575

    const int tid  = threadIdx.x;
    const int wv   = tid >> 6;
    const int wch  = wv >> 1;          // code half (0/1) -> 128-code rows
    const int wtc  = wv & 1;           // token col (0/1) -> 64 tokens
    const int lane = tid & 63;
    const int h    = lane >> 5;
    const int l31  = lane & 31;
    const int rx   = l31 & 7;          // fragment-row swizzle bits
    const int m0   = blockIdx.x * 128;
    const int scode0 = blockIdx.y * SPLIT_CODES;

    // staging roles: 8 threads per row, thread covers rows srow8+32j, quantum sq
    const int srow8 = tid >> 3;
    const int sq    = tid & 7;
    const int sxor  = sq ^ (srow8 & 7);

    uint32 k1[2], k2[2], k3[2];
    #pragma unroll
    for (int c = 0; c < 2; ++c) { k1[c] = 0xFFFFFFFFu; k2[c] = 0xFFFFFFFFu; k3[c] = 0xFFFFFFFFu; }

    for (int p = 0; p < PANELS; ++p) {
        const int code0 = scode0 + p * 256;

        f32x16 acc[4][2];
        #pragma unroll
        for (int i = 0; i < 4; ++i)
            #pragma unroll
            for (int c = 0; c < 2; ++c)
                #pragma unroll
                for (int e = 0; e < 16; ++e) acc[i][c][e] = 0.f;

        for (int kc = 0; kc < 8; ++kc) {
            __syncthreads();   // previous chunk's reads complete
            // stage A (codes): 256 rows x 64 k; 1KB-contiguous per wave-instr
            #pragma unroll
            for (int j = 0; j < 8; ++j) {
                int r = srow8 + 32 * j;
                uint4 v = *(const uint4*)(wb + (size_t)(code0 + r) * DIM + kc * 64 + sq * 8);
                *(uint4*)&POOL[r * 64 + sxor * 8] = v;
            }
            // stage B (tokens): 128 rows x 64 k
            #pragma unroll
            for (int j = 0; j < 4; ++j) {
                int r = srow8 + 32 * j;
                uint4 v = *(const uint4*)(xb + (size_t)(m0 + r) * DIM + kc * 64 + sq * 8);
                *(uint4*)&POOL[16384 + r * 64 + sxor * 8] = v;
            }
            __syncthreads();

            #pragma unroll
            for (int ks = 0; ks < 4; ++ks) {
                const int qa = ks * 2 + h;
                s16x8 af[4], bf[2];
                #pragma unroll
                for (int i = 0; i < 4; ++i) {
                    const int r = wch * 128 + i * 32 + l31;
                    af[i] = *(const s16x8*)&POOL[r * 64 + ((qa ^ rx)) * 8];
                }
                #pragma unroll
                for (int c = 0; c < 2; ++c) {
                    const int n = wtc * 64 + c * 32 + l31;
                    bf[c] = *(const s16x8*)&POOL[16384 + n * 64 + ((qa ^ rx)) * 8];
                }
                #pragma unroll
                for (int i = 0; i < 4; ++i)
                    #pragma unroll
                    for (int c = 0; c < 2; ++c)
                        acc[i][c] = __builtin_amdgcn_mfma_f32_32x32x16_bf16(af[i], bf[c], acc[i][c], 0, 0, 0);
            }
        }

        // fold panel: code row m = (e&3)+8*(e>>2)+4*h + i*32 + wch*128 + code0
        #pragma unroll
        for (int i = 0; i < 4; ++i) {
            const int cb = code0 + wch * 128 + i * 32 + h * 4;
            #pragma unroll
            for (int g = 0; g < 4; ++g) {
                float4 wq = *(const float4*)&w2f[cb + g * 8];
                float wa[4] = {wq.x + BIAS, wq.y + BIAS, wq.z + BIAS, wq.w + BIAS};
                #pragma unroll
                for (int e2 = 0; e2 < 4; ++e2) {
                    const uint32 code = (uint32)(cb + g * 8 + e2);
                    #pragma unroll
                    for (int c = 0; c < 2; ++c) {
                        float s = fmaf(-2.0f, acc[i][c][g * 4 + e2], wa[e2]);
                        uint32 key = (__float_as_uint(s) & 0xFFFFF000u) | code;
                        ins3(key, k1[c], k2[c], k3[c]);
                    }
                }
            }
        }
    }

    // merge: 12 entries per token (2 code-halves x 2 lane-halves x 3) -> top-6
    __syncthreads();
    uint32* MS = (uint32*)&POOL[16384];        // 128 tokens x 12 u32 = 6KB
    #pragma unroll
    for (int c = 0; c < 2; ++c) {
        const int t = wtc * 64 + c * 32 + l31;
        const int base = t * 12 + wch * 6 + h * 3;
        MS[base] = k1[c]; MS[base + 1] = k2[c]; MS[base + 2] = k3[c];
    }
    __syncthreads();
    if (tid < 128) {
        uint32 best[6];
        #pragma unroll
        for (int c = 0; c < 6; ++c) best[c] = 0xFFFFFFFFu;
        #pragma unroll
        for (int s = 0; s < 12; ++s) {
            uint32 v = MS[tid * 12 + s];
            if (v < best[5]) {
                best[5] = v;
                #pragma unroll
                for (int q = 5; q > 0; --q)
                    if (best[q] < best[q - 1]) { uint32 tv = best[q]; best[q] = best[q - 1]; best[q - 1] = tv; }
            }
        }
        uint32* dst = candPart + ((size_t)blockIdx.y * N_TOK + (m0 + tid)) * 6;
        #pragma unroll
        for (int c = 0; c < 6; ++c) dst[c] = best[c];
    }
}

// ---------------------------------------------------------------------------
// Fused: merge split candidates -> top-8, np-exact refine (R3-verified math),
// then gather/straight-through/loss/counts epilogue. One wave per token.
// ---------------------------------------------------------------------------
__global__ __launch_bounds__(256) void refine_gather_kernel(const float* __restrict__ x,
                                                            const float* __restrict__ w,
                                                            const float* __restrict__ x2np,
                                                            const float* __restrict__ w2np,
                                                            const uint32* __restrict__ candPart,
                                                            float* __restrict__ out_q,
                                                            float* __restrict__ out_loss,
                                                            float* __restrict__ out_ind,
                                                            int* __restrict__ counts) {
    const int t    = blockIdx.x * 4 + (threadIdx.x >> 6);
    const int lane = threadIdx.x & 63;

    const float* xr = x + (size_t)t * DIM;
    float xv[8];
    #pragma unroll
    for (int j = 0; j < 8; ++j) xv[j] = xr[lane + 64 * j];
    const float x2 = x2np[t];

    // all lanes redundantly merge the 24 split-entries (uniform loads)
    uint32 best[NCAND];
    #pragma unroll
    for (int c = 0; c < NCAND; ++c) best[c] = 0xFFFFFFFFu;
    for (int s = 0; s < NSPLIT; ++s) {
        const uint32* src = candPart + ((size_t)s * N_TOK + t) * 6;
        #pragma unroll
        for (int c = 0; c < 6; ++c) {
            uint32 v = src[c];
            if (v < best[NCAND - 1]) {
                best[NCAND - 1] = v;
                #pragma unroll
                for (int q = NCAND - 1; q > 0; --q)
                    if (best[q] < best[q - 1]) { uint32 tv = best[q]; best[q] = best[q - 1]; best[q - 1] = tv; }
            }
        }
    }

    float bd = 3.4e38f;
    int   bk = 0x7fffffff;
    for (int c = 0; c < NCAND; ++c) {
        int k = (int)(best[c] & 0xFFFu);
        const float* wr = w + (size_t)k * DIM;
        double m = 0.0;
        #pragma unroll
        for (int j = 0; j < 8; ++j)
            m = fma((double)xv[j], (double)wr[lane + 64 * j], m);
        #pragma unroll
        for (int off = 32; off >= 1; off >>= 1) m += __shfl_down(m, off);
        if (lane == 0) {
            #pragma clang fp contract(off)
            float m32 = (float)m;
            float T1  = x2 + w2np[k];
            float d   = T1 - 2.0f * m32;
            if (d < bd || (d == bd && k < bk)) { bd = d; bk = k; }
        }
    }
    bk = __shfl(bk, 0);

    // epilogue: straight-through output + loss + counts
    const float* wr = w + (size_t)bk * DIM;
    float* qo = out_q + (size_t)t * DIM;
    float ss = 0.f;
    #pragma unroll
    for (int j = 0; j < 8; ++j) {
        const int e = lane + 64 * j;
        float wv = wr[e];
        float d = wv - xv[j];
        float o = xv[j] + d;
        qo[e] = o;
        ss += d * d;
    }
    #pragma unroll
    for (int off = 32; off >= 1; off >>= 1) ss += __shfl_down(ss, off);
    if (lane == 0) {
        float lm = ss * (1.0f / DIM);
        out_loss[t] = lm + COMMIT * lm;
        out_ind[t] = (float)bk;
        atomicAdd(&counts[bk], 1);
    }
}

// ---------------------------------------------------------------------------
// perplexity (R3-verified).
// ---------------------------------------------------------------------------
__global__ __launch_bounds__(256) void perplex_kernel(const int* __restrict__ counts,
                                                      float* __restrict__ out2) {
    __shared__ double red[4];
    const int tid = threadIdx.x;
    const int lane = tid & 63;
    const int wid = tid >> 6;
    double s = 0.0;
    for (int t = tid; t < K_CODES; t += 256) {
        int c = counts[t];
        if (c) {
            double p = (double)c * (1.0 / N_TOK);
            s += p * log(p + 1e-10);
        }
    }
    #pragma unroll
    for (int off = 32; off >= 1; off >>= 1) s += __shfl_down(s, off);
    if (lane == 0) red[wid] = s;
    __syncthreads();
    if (tid == 0) {
        double t = red[0] + red[1] + red[2] + red[3];
        out2[0] = (float)exp(-t);
    }
}

// ---------------------------------------------------------------------------
extern "C" void kernel_launch(void* const* d_in, const int* in_sizes, int n_in,
                              void* d_out, int out_size, void* d_ws, size_t ws_size,
                              hipStream_t stream) {
    const float* x = (const float*)d_in[0];
    const float* w = (const float*)d_in[1];

    float* out0 = (float*)d_out;                       // quantized_st [N,D]
    float* out1 = out0 + (size_t)N_TOK * DIM;          // loss [N]
    float* out2 = out1 + N_TOK;                        // perplexity [1]
    float* out3 = out2 + 1;                            // indices [N] (as float)

    uint32* candPart = (uint32*)d_ws;                             // 4*32768*6
    float*  x2np     = (float*)(candPart + (size_t)NSPLIT * N_TOK * 6);
    float*  w2np     = x2np + N_TOK;
    int*    counts   = (int*)(w2np + K_CODES);
    u16*    x_bf     = (u16*)(counts + K_CODES);                  // N_TOK*DIM
    u16*    w_bf     = x_bf + (size_t)N_TOK * DIM;                // K_CODES*DIM

    hipMemsetAsync(counts, 0, K_CODES * sizeof(int), stream);

    fuse_prep_kernel<<<N_TOK / 32, 256, 0, stream>>>(x, x2np, x_bf, N_TOK, N_TOK * DIM / 4);
    fuse_prep_kernel<<<K_CODES / 32, 256, 0, stream>>>(w, w2np, w_bf, K_CODES, K_CODES * DIM / 4);
    screen_kernel<<<dim3(N_TOK / 128, NSPLIT), 256, 0, stream>>>(x_bf, w_bf, w2np, candPart);
    refine_gather_kernel<<<N_TOK / 4, 256, 0, stream>>>(x, w, x2np, w2np, candPart,
                                                        out0, out1, out3, counts);
    perplex_kernel<<<1, 256, 0, stream>>>(counts, out2);
}